// Round 2
// baseline (2631.866 us; speedup 1.0000x reference)
//
#include <hip/hip_runtime.h>
#include <hip/hip_bf16.h>

// Problem constants (F is hard-coded 31 in the reference / TAG)
#define FDIM 31
#define FPAD 32   // padded row stride (floats) -> 128B rows, float4-friendly

// ---------------------------------------------------------------- utilities

__global__ void deg_hist_kernel(const int* __restrict__ dst, int* __restrict__ deg, int E) {
    int e = blockIdx.x * 256 + threadIdx.x;
    if (e < E) atomicAdd(&deg[dst[e]], 1);
}

// per-block inclusive scan -> writes block-local EXCLUSIVE prefix to out, block total to partials
__global__ void scan_block_kernel(const int* __restrict__ deg, int* __restrict__ out,
                                  int* __restrict__ partials, int N) {
    __shared__ int s[256];
    int i = blockIdx.x * 256 + threadIdx.x;
    int v = (i < N) ? deg[i] : 0;
    s[threadIdx.x] = v;
    __syncthreads();
    for (int off = 1; off < 256; off <<= 1) {
        int t = (threadIdx.x >= off) ? s[threadIdx.x - off] : 0;
        __syncthreads();
        s[threadIdx.x] += t;
        __syncthreads();
    }
    if (i < N) out[i] = s[threadIdx.x] - v;  // exclusive within block
    if (threadIdx.x == 255) partials[blockIdx.x] = s[255];
}

// single-block chunked exclusive scan of partials (in place)
__global__ void scan_partials_kernel(int* __restrict__ partials, int nb) {
    __shared__ int s[256];
    __shared__ int carry;
    if (threadIdx.x == 0) carry = 0;
    __syncthreads();
    for (int base = 0; base < nb; base += 256) {
        int i = base + threadIdx.x;
        int v = (i < nb) ? partials[i] : 0;
        s[threadIdx.x] = v;
        __syncthreads();
        for (int off = 1; off < 256; off <<= 1) {
            int t = (threadIdx.x >= off) ? s[threadIdx.x - off] : 0;
            __syncthreads();
            s[threadIdx.x] += t;
            __syncthreads();
        }
        int res = carry + s[threadIdx.x] - v;  // global exclusive
        int tot = s[255];
        __syncthreads();
        if (i < nb) partials[i] = res;
        if (threadIdx.x == 0) carry += tot;
        __syncthreads();
    }
}

__global__ void finalize_kernel(int* __restrict__ rowptr, const int* __restrict__ partials,
                                const int* __restrict__ deg, int* __restrict__ cursor,
                                float* __restrict__ normv, int N, int E) {
    int i = blockIdx.x * 256 + threadIdx.x;
    if (i >= N) return;
    int r = rowptr[i] + partials[i >> 8];
    rowptr[i] = r;
    cursor[i] = r;
    int d = deg[i];
    normv[i] = rsqrtf((float)(d > 0 ? d : 1));
    if (i == 0) rowptr[N] = E;
}

__global__ void fill_csr_kernel(const int* __restrict__ src, const int* __restrict__ dst,
                                int* __restrict__ cursor, int* __restrict__ col, int E) {
    int e = blockIdx.x * 256 + threadIdx.x;
    if (e >= E) return;
    int p = atomicAdd(&cursor[dst[e]], 1);
    col[p] = src[e];
}

__global__ void cast_x_kernel(const float* __restrict__ x, float* __restrict__ A, int N) {
    int idx = blockIdx.x * 256 + threadIdx.x;
    if (idx >= N * FPAD) return;
    int n = idx >> 5, f = idx & 31;
    A[idx] = (f < FDIM) ? x[(size_t)n * FDIM + f] : 0.0f;
}

// ------------------------------------------------------------------ SpMM hop
// Hout[n][:] = norm[n] * sum_{e: dst=n} norm[col[e]] * Hin[col[e]][:]
// 8 lanes per node, each lane owns one float4 chunk of the 32-float row.
__global__ __launch_bounds__(256) void spmm_kernel(const float* __restrict__ Hin,
                                                   float* __restrict__ Hout,
                                                   const int* __restrict__ rowptr,
                                                   const int* __restrict__ col,
                                                   const float* __restrict__ normv, int N) {
    int node = blockIdx.x * 32 + (threadIdx.x >> 3);
    int sub = threadIdx.x & 7;
    if (node >= N) return;
    int s = rowptr[node], e = rowptr[node + 1];
    float4 acc = make_float4(0.f, 0.f, 0.f, 0.f);
    for (int k = s; k < e; ++k) {
        int c = col[k];
        float ns = normv[c];
        float4 v = *(const float4*)(Hin + (size_t)c * FPAD + sub * 4);
        acc.x = fmaf(ns, v.x, acc.x);
        acc.y = fmaf(ns, v.y, acc.y);
        acc.z = fmaf(ns, v.z, acc.z);
        acc.w = fmaf(ns, v.w, acc.w);
    }
    float nn = normv[node];
    float4 o = make_float4(nn * acc.x, nn * acc.y, nn * acc.z, nn * acc.w);
    *(float4*)(Hout + (size_t)node * FPAD + sub * 4) = o;
}

// ------------------------------------------------------- fused linear + relu
// out_h[n][j] = relu( bias[j] + sum_i [A|Bh|Ch][n][i] * W[i][j] )   (W is 93x31 fp32)
__global__ __launch_bounds__(256) void linear_relu_kernel(const float* __restrict__ A,
                                                          const float* __restrict__ Bh,
                                                          const float* __restrict__ Ch,
                                                          const float* __restrict__ W,
                                                          const float* __restrict__ bias,
                                                          float* __restrict__ out_h, int N) {
    int n = blockIdx.x * 256 + threadIdx.x;
    if (n >= N) return;
    float out[FDIM];
#pragma unroll
    for (int j = 0; j < FDIM; ++j) out[j] = bias[j];
#pragma unroll 1
    for (int blk = 0; blk < 3; ++blk) {
        const float* bp = (blk == 0) ? A : ((blk == 1) ? Bh : Ch);
        const float4* r4p = (const float4*)(bp + (size_t)n * FPAD);
        float4 r4[8];
#pragma unroll
        for (int q = 0; q < 8; ++q) r4[q] = r4p[q];
        const float* rr = (const float*)r4;
        const float* Wb = W + blk * FDIM * FDIM;
#pragma unroll
        for (int i = 0; i < FDIM; ++i) {
            float v = rr[i];
#pragma unroll
            for (int j = 0; j < FDIM; ++j) out[j] = fmaf(v, Wb[i * FDIM + j], out[j]);
        }
    }
    float* o = out_h + (size_t)n * FPAD;
#pragma unroll
    for (int j = 0; j < FDIM; ++j) o[j] = fmaxf(out[j], 0.0f);
}

// ----------------------------------------------------------------- pooling

__global__ void gate_kernel(const float* __restrict__ H, const float* __restrict__ wgf,
                            const float* __restrict__ bgf, float* __restrict__ gate, int N) {
    int n = blockIdx.x * 256 + threadIdx.x;
    if (n >= N) return;
    float acc = bgf[0];
    const float* h = H + (size_t)n * FPAD;
#pragma unroll
    for (int f = 0; f < FDIM; ++f) acc = fmaf(h[f], wgf[f], acc);
    gate[n] = acc;
}

__global__ void boundaries_kernel(const int* __restrict__ gid, int* __restrict__ gstart, int N) {
    int n = blockIdx.x * 256 + threadIdx.x;
    if (n >= N) return;
    int g = gid[n];
    if (n == 0 || gid[n - 1] != g) gstart[g] = n;
    if (n == N - 1) gstart[g + 1] = N;
}

__global__ void soff_scan_kernel(const int* __restrict__ num, int* __restrict__ soff, int Bn) {
    if (threadIdx.x == 0 && blockIdx.x == 0) {
        int acc = 0;
        soff[0] = 0;
        for (int i = 0; i < Bn; ++i) { acc += num[i]; soff[i + 1] = acc; }
    }
}

__global__ __launch_bounds__(64) void graph_reduce_kernel(const float* __restrict__ gate,
                                                          const int* __restrict__ gstart,
                                                          const int* __restrict__ soff, int Bn,
                                                          float* __restrict__ gmax,
                                                          float* __restrict__ gden) {
    int g = blockIdx.x;
    int Gtot = soff[Bn];
    if (g >= Gtot) return;
    int s = gstart[g], e = gstart[g + 1];
    float m = -1e30f;
    for (int n = s + threadIdx.x; n < e; n += 64) m = fmaxf(m, gate[n]);
#pragma unroll
    for (int o = 32; o > 0; o >>= 1) m = fmaxf(m, __shfl_xor(m, o));
    float d = 0.0f;
    for (int n = s + threadIdx.x; n < e; n += 64) d += expf(gate[n] - m);
#pragma unroll
    for (int o = 32; o > 0; o >>= 1) d += __shfl_xor(d, o);
    if (threadIdx.x == 0) { gmax[g] = m; gden[g] = d; }
}

__global__ __launch_bounds__(64) void rep_scatter_kernel(const float* __restrict__ H,
                                                         const float* __restrict__ gate,
                                                         const int* __restrict__ gstart,
                                                         const int* __restrict__ soff, int Bn,
                                                         int MAXG,
                                                         const float* __restrict__ gmax,
                                                         const float* __restrict__ gden,
                                                         float* __restrict__ out) {
    int g = blockIdx.x;
    int Gtot = soff[Bn];
    if (g >= Gtot) return;
    int s = 0;
    while (soff[s + 1] <= g) ++s;  // sample id (searchsorted right)
    int pos = g - soff[s];
    int ns = gstart[g], ne = gstart[g + 1];
    float m = gmax[g], den = gden[g];
    int t = threadIdx.x;
    if (t < FDIM) {
        float acc = 0.0f;
        for (int n = ns; n < ne; ++n) acc += expf(gate[n] - m) * H[(size_t)n * FPAD + t];
        out[((size_t)s * MAXG + pos) * FDIM + t] = acc / den;
    }
}

// ------------------------------------------------------------------ launcher

extern "C" void kernel_launch(void* const* d_in, const int* in_sizes, int n_in,
                              void* d_out, int out_size, void* d_ws, size_t ws_size,
                              hipStream_t stream) {
    const float* x      = (const float*)d_in[0];
    const float* Ws     = (const float*)d_in[1];
    const float* bs     = (const float*)d_in[2];
    const float* w_gate = (const float*)d_in[3];
    const float* b_gate = (const float*)d_in[4];
    const int* src       = (const int*)d_in[5];
    const int* dst       = (const int*)d_in[6];
    const int* graph_ids = (const int*)d_in[7];
    const int* num       = (const int*)d_in[8];
    float* out  = (float*)d_out;

    const int N  = in_sizes[7];
    const int E  = in_sizes[5];
    const int Bn = in_sizes[8];
    const int F  = in_sizes[3];            // 31
    const int L  = in_sizes[2] / F;        // 5
    const int nW = in_sizes[1];            // L * 3F * F
    const int WperL = nW / L;              // 3F*F = 93*31
    const int MAXG = out_size / (Bn * F);  // 120
    const int Gmax = Bn * MAXG;            // upper bound on G (actual G on device)

    // ---- workspace carve-up
    char* p = (char*)d_ws;
    auto alloc = [&](size_t bytes) {
        void* r = (void*)p;
        p += (bytes + 255) & ~(size_t)255;
        return r;
    };
    float* HA    = (float*)alloc((size_t)N * FPAD * 4);
    float* HB    = (float*)alloc((size_t)N * FPAD * 4);
    float* HC    = (float*)alloc((size_t)N * FPAD * 4);
    int*   colw  = (int*)alloc((size_t)E * 4);
    int*   deg   = (int*)alloc((size_t)N * 4);
    int*   rowp  = (int*)alloc((size_t)(N + 1) * 4);
    int*   curs  = (int*)alloc((size_t)N * 4);
    float* normv = (float*)alloc((size_t)N * 4);
    float* gatev = (float*)alloc((size_t)N * 4);
    float* Wf    = (float*)alloc((size_t)nW * 4);   // unused in fp32 path (kept for layout stability)
    float* bf    = (float*)alloc((size_t)L * F * 4);
    float* wgf   = (float*)alloc((size_t)F * 4);
    float* bgf   = (float*)alloc(4);
    float* gmax  = (float*)alloc((size_t)Gmax * 4);
    float* gden  = (float*)alloc((size_t)Gmax * 4);
    int*   gstart= (int*)alloc((size_t)(Gmax + 1) * 4);
    int*   soff  = (int*)alloc((size_t)(Bn + 1) * 4);
    const int NB = (N + 255) / 256;
    int*   parts = (int*)alloc((size_t)NB * 4);
    (void)Wf; (void)bf; (void)wgf; (void)bgf;

    // ---- zero init (ws/out are poisoned 0xAA before every call)
    hipMemsetAsync(deg, 0, (size_t)N * 4, stream);
    hipMemsetAsync(gstart, 0, (size_t)(Gmax + 1) * 4, stream);
    hipMemsetAsync(d_out, 0, (size_t)out_size * sizeof(float), stream);

    const int EB = (E + 255) / 256;

    // ---- CSR build (by dst) + norms
    deg_hist_kernel<<<EB, 256, 0, stream>>>(dst, deg, E);
    scan_block_kernel<<<NB, 256, 0, stream>>>(deg, rowp, parts, N);
    scan_partials_kernel<<<1, 256, 0, stream>>>(parts, NB);
    finalize_kernel<<<NB, 256, 0, stream>>>(rowp, parts, deg, curs, normv, N, E);
    fill_csr_kernel<<<EB, 256, 0, stream>>>(src, dst, curs, colw, E);

    // ---- input layout (pad 31 -> 32)
    cast_x_kernel<<<(N * FPAD + 255) / 256, 256, 0, stream>>>(x, HA, N);

    // ---- 5 TAGConv layers (params read directly from d_in, fp32)
    const int SB = (N + 31) / 32;
    for (int l = 0; l < L; ++l) {
        spmm_kernel<<<SB, 256, 0, stream>>>(HA, HB, rowp, colw, normv, N);
        spmm_kernel<<<SB, 256, 0, stream>>>(HB, HC, rowp, colw, normv, N);
        linear_relu_kernel<<<NB, 256, 0, stream>>>(HA, HB, HC, Ws + (size_t)l * WperL,
                                                   bs + (size_t)l * F, HA, N);
    }

    // ---- gated attention pooling + padded scatter
    gate_kernel<<<NB, 256, 0, stream>>>(HA, w_gate, b_gate, gatev, N);
    boundaries_kernel<<<NB, 256, 0, stream>>>(graph_ids, gstart, N);
    soff_scan_kernel<<<1, 64, 0, stream>>>(num, soff, Bn);
    graph_reduce_kernel<<<Gmax, 64, 0, stream>>>(gatev, gstart, soff, Bn, gmax, gden);
    rep_scatter_kernel<<<Gmax, 64, 0, stream>>>(HA, gatev, gstart, soff, Bn, MAXG,
                                                gmax, gden, out);
    (void)n_in; (void)ws_size;
}

// Round 4
// 2180.700 us; speedup vs baseline: 1.2069x; 1.2069x over previous
//
#include <hip/hip_runtime.h>
#include <hip/hip_bf16.h>

// Problem constants (F is hard-coded 31 in the reference / TAG)
#define FDIM 31
#define FPAD 32   // padded row stride (floats) -> 128B rows, float4-friendly

// Coarse bucketing for CSR build: 2048 nodes per bucket
#define CBITS 11
#define CW    (1 << CBITS)
#define MAXBUK 256
#define TILE 4096

// --------------------------------------------------- multisplit (level 1)
// Race-free: phase1 histogram (re-reads dst), phase2 scan + global-base claim,
// phase3 LDS reorder (writes ordered[] only), phase4 flush with binary search
// on lofs to recover each sorted slot's bucket. ~196 coalesced global atomics
// per 4096-edge tile instead of 4096 scattered ones.
__global__ __launch_bounds__(256) void multisplit_kernel(
    const int* __restrict__ src, const int* __restrict__ dst,
    int* __restrict__ gcnt,           // [nbuk] running per-bucket counts (pre-zeroed)
    int* __restrict__ bucketed,       // [nbuk * cap] packed edges
    int cap, int E, int nbuk)
{
    __shared__ int ordered[TILE];     // 16 KB packed edges, bucket-grouped
    __shared__ int hist[MAXBUK];
    __shared__ int lofs[MAXBUK + 1];
    __shared__ int base_[MAXBUK];
    __shared__ int cur[MAXBUK];
    const int tid = threadIdx.x;
    const int e0 = blockIdx.x * TILE;
    const int n = min(TILE, E - e0);
    if (tid < MAXBUK) hist[tid] = 0;
    __syncthreads();
    for (int i = tid; i < n; i += 256)
        atomicAdd(&hist[dst[e0 + i] >> CBITS], 1);        // LDS atomic
    __syncthreads();
    if (tid == 0) {                   // serial exclusive scan over <=256 buckets
        int a = 0;
        for (int b = 0; b < nbuk; ++b) { lofs[b] = a; a += hist[b]; }
        lofs[nbuk] = a;               // == n
    }
    __syncthreads();
    if (tid < nbuk) {
        int h = hist[tid];
        base_[tid] = h ? atomicAdd(&gcnt[tid], h) : 0;    // coalesced global atomic
        cur[tid] = lofs[tid];
    }
    __syncthreads();
    // reorder into bucket-grouped order within the tile (writes ordered[] only)
    for (int i = tid; i < n; i += 256) {
        int s = src[e0 + i], d = dst[e0 + i];             // L2-hot re-read
        int b = d >> CBITS;
        int r = atomicAdd(&cur[b], 1);                    // LDS atomic
        ordered[r] = (s << CBITS) | (d & (CW - 1));
    }
    __syncthreads();
    // flush: slot i belongs to bucket b with lofs[b] <= i < lofs[b+1]
    for (int i = tid; i < n; i += 256) {
        int lo = 0, hi = nbuk;
        while (hi - lo > 1) {
            int mid = (lo + hi) >> 1;
            if (lofs[mid] <= i) lo = mid; else hi = mid;
        }
        int b = lo;
        int pos = base_[b] + (i - lofs[b]);
        if (pos < cap) bucketed[(size_t)b * cap + pos] = ordered[i];
    }
}

// --------------------------------------------------- per-bucket degree (level 2a)
__global__ __launch_bounds__(1024) void bucket_deg_kernel(
    const int* __restrict__ bucketed, const int* __restrict__ gcnt,
    int* __restrict__ deg, int cap, int N)
{
    __shared__ int hist[CW];
    const int b = blockIdx.x, tid = threadIdx.x;
    for (int t = tid; t < CW; t += 1024) hist[t] = 0;
    __syncthreads();
    const int cnt = min(gcnt[b], cap);
    const int* reg = bucketed + (size_t)b * cap;
    for (int i = tid; i < cnt; i += 1024)
        atomicAdd(&hist[reg[i] & (CW - 1)], 1);           // LDS atomic
    __syncthreads();
    const int base_node = b << CBITS;
    for (int t = tid; t < CW; t += 1024) {
        int node = base_node + t;
        if (node < N) deg[node] = hist[t];
    }
}

// --------------------------------------------------- per-bucket CSR fill (level 2b)
__global__ __launch_bounds__(1024) void bucket_fill_kernel(
    const int* __restrict__ bucketed, const int* __restrict__ gcnt,
    const int* __restrict__ rowptr, int* __restrict__ col, int cap, int N)
{
    __shared__ int lcur[CW];
    const int b = blockIdx.x, tid = threadIdx.x;
    const int base_node = b << CBITS;
    for (int t = tid; t < CW; t += 1024) {
        int node = base_node + t;
        lcur[t] = (node < N) ? rowptr[node] : 0;
    }
    __syncthreads();
    const int cnt = min(gcnt[b], cap);
    const int* reg = bucketed + (size_t)b * cap;
    for (int i = tid; i < cnt; i += 1024) {
        int e = reg[i];
        int p = atomicAdd(&lcur[e & (CW - 1)], 1);        // LDS atomic
        col[p] = e >> CBITS;                              // writes stay in bucket's
    }                                                     //  contiguous L2-resident range
}

// --------------------------------------------------- scans (unchanged)

__global__ void scan_block_kernel(const int* __restrict__ deg, int* __restrict__ out,
                                  int* __restrict__ partials, int N) {
    __shared__ int s[256];
    int i = blockIdx.x * 256 + threadIdx.x;
    int v = (i < N) ? deg[i] : 0;
    s[threadIdx.x] = v;
    __syncthreads();
    for (int off = 1; off < 256; off <<= 1) {
        int t = (threadIdx.x >= off) ? s[threadIdx.x - off] : 0;
        __syncthreads();
        s[threadIdx.x] += t;
        __syncthreads();
    }
    if (i < N) out[i] = s[threadIdx.x] - v;  // exclusive within block
    if (threadIdx.x == 255) partials[blockIdx.x] = s[255];
}

__global__ void scan_partials_kernel(int* __restrict__ partials, int nb) {
    __shared__ int s[256];
    __shared__ int carry;
    if (threadIdx.x == 0) carry = 0;
    __syncthreads();
    for (int base = 0; base < nb; base += 256) {
        int i = base + threadIdx.x;
        int v = (i < nb) ? partials[i] : 0;
        s[threadIdx.x] = v;
        __syncthreads();
        for (int off = 1; off < 256; off <<= 1) {
            int t = (threadIdx.x >= off) ? s[threadIdx.x - off] : 0;
            __syncthreads();
            s[threadIdx.x] += t;
            __syncthreads();
        }
        int res = carry + s[threadIdx.x] - v;  // global exclusive
        int tot = s[255];
        __syncthreads();
        if (i < nb) partials[i] = res;
        if (threadIdx.x == 0) carry += tot;
        __syncthreads();
    }
}

__global__ void finalize_kernel(int* __restrict__ rowptr, const int* __restrict__ partials,
                                const int* __restrict__ deg,
                                float* __restrict__ normv, int N, int E) {
    int i = blockIdx.x * 256 + threadIdx.x;
    if (i >= N) return;
    int r = rowptr[i] + partials[i >> 8];
    rowptr[i] = r;
    int d = deg[i];
    normv[i] = rsqrtf((float)(d > 0 ? d : 1));
    if (i == 0) rowptr[N] = E;
}

__global__ void cast_x_kernel(const float* __restrict__ x, float* __restrict__ A, int N) {
    int idx = blockIdx.x * 256 + threadIdx.x;
    if (idx >= N * FPAD) return;
    int n = idx >> 5, f = idx & 31;
    A[idx] = (f < FDIM) ? x[(size_t)n * FDIM + f] : 0.0f;
}

// ------------------------------------------------------------------ SpMM hop
__global__ __launch_bounds__(256) void spmm_kernel(const float* __restrict__ Hin,
                                                   float* __restrict__ Hout,
                                                   const int* __restrict__ rowptr,
                                                   const int* __restrict__ col,
                                                   const float* __restrict__ normv, int N) {
    int node = blockIdx.x * 32 + (threadIdx.x >> 3);
    int sub = threadIdx.x & 7;
    if (node >= N) return;
    int s = rowptr[node], e = rowptr[node + 1];
    float4 acc = make_float4(0.f, 0.f, 0.f, 0.f);
    for (int k = s; k < e; ++k) {
        int c = col[k];
        float ns = normv[c];
        float4 v = *(const float4*)(Hin + (size_t)c * FPAD + sub * 4);
        acc.x = fmaf(ns, v.x, acc.x);
        acc.y = fmaf(ns, v.y, acc.y);
        acc.z = fmaf(ns, v.z, acc.z);
        acc.w = fmaf(ns, v.w, acc.w);
    }
    float nn = normv[node];
    float4 o = make_float4(nn * acc.x, nn * acc.y, nn * acc.z, nn * acc.w);
    *(float4*)(Hout + (size_t)node * FPAD + sub * 4) = o;
}

// ------------------------------------------------------- fused linear + relu
__global__ __launch_bounds__(256) void linear_relu_kernel(const float* __restrict__ A,
                                                          const float* __restrict__ Bh,
                                                          const float* __restrict__ Ch,
                                                          const float* __restrict__ W,
                                                          const float* __restrict__ bias,
                                                          float* __restrict__ out_h, int N) {
    int n = blockIdx.x * 256 + threadIdx.x;
    if (n >= N) return;
    float out[FDIM];
#pragma unroll
    for (int j = 0; j < FDIM; ++j) out[j] = bias[j];
#pragma unroll 1
    for (int blk = 0; blk < 3; ++blk) {
        const float* bp = (blk == 0) ? A : ((blk == 1) ? Bh : Ch);
        const float4* r4p = (const float4*)(bp + (size_t)n * FPAD);
        float4 r4[8];
#pragma unroll
        for (int q = 0; q < 8; ++q) r4[q] = r4p[q];
        const float* rr = (const float*)r4;
        const float* Wb = W + blk * FDIM * FDIM;
#pragma unroll
        for (int i = 0; i < FDIM; ++i) {
            float v = rr[i];
#pragma unroll
            for (int j = 0; j < FDIM; ++j) out[j] = fmaf(v, Wb[i * FDIM + j], out[j]);
        }
    }
    float* o = out_h + (size_t)n * FPAD;
#pragma unroll
    for (int j = 0; j < FDIM; ++j) o[j] = fmaxf(out[j], 0.0f);
}

// ----------------------------------------------------------------- pooling

__global__ void gate_kernel(const float* __restrict__ H, const float* __restrict__ wgf,
                            const float* __restrict__ bgf, float* __restrict__ gate, int N) {
    int n = blockIdx.x * 256 + threadIdx.x;
    if (n >= N) return;
    float acc = bgf[0];
    const float* h = H + (size_t)n * FPAD;
#pragma unroll
    for (int f = 0; f < FDIM; ++f) acc = fmaf(h[f], wgf[f], acc);
    gate[n] = acc;
}

__global__ void boundaries_kernel(const int* __restrict__ gid, int* __restrict__ gstart, int N) {
    int n = blockIdx.x * 256 + threadIdx.x;
    if (n >= N) return;
    int g = gid[n];
    if (n == 0 || gid[n - 1] != g) gstart[g] = n;
    if (n == N - 1) gstart[g + 1] = N;
}

__global__ void soff_scan_kernel(const int* __restrict__ num, int* __restrict__ soff, int Bn) {
    if (threadIdx.x == 0 && blockIdx.x == 0) {
        int acc = 0;
        soff[0] = 0;
        for (int i = 0; i < Bn; ++i) { acc += num[i]; soff[i + 1] = acc; }
    }
}

__global__ __launch_bounds__(64) void graph_reduce_kernel(const float* __restrict__ gate,
                                                          const int* __restrict__ gstart,
                                                          const int* __restrict__ soff, int Bn,
                                                          float* __restrict__ gmax,
                                                          float* __restrict__ gden) {
    int g = blockIdx.x;
    int Gtot = soff[Bn];
    if (g >= Gtot) return;
    int s = gstart[g], e = gstart[g + 1];
    float m = -1e30f;
    for (int n = s + threadIdx.x; n < e; n += 64) m = fmaxf(m, gate[n]);
#pragma unroll
    for (int o = 32; o > 0; o >>= 1) m = fmaxf(m, __shfl_xor(m, o));
    float d = 0.0f;
    for (int n = s + threadIdx.x; n < e; n += 64) d += expf(gate[n] - m);
#pragma unroll
    for (int o = 32; o > 0; o >>= 1) d += __shfl_xor(d, o);
    if (threadIdx.x == 0) { gmax[g] = m; gden[g] = d; }
}

__global__ __launch_bounds__(64) void rep_scatter_kernel(const float* __restrict__ H,
                                                         const float* __restrict__ gate,
                                                         const int* __restrict__ gstart,
                                                         const int* __restrict__ soff, int Bn,
                                                         int MAXG,
                                                         const float* __restrict__ gmax,
                                                         const float* __restrict__ gden,
                                                         float* __restrict__ out) {
    int g = blockIdx.x;
    int Gtot = soff[Bn];
    if (g >= Gtot) return;
    int s = 0;
    while (soff[s + 1] <= g) ++s;  // sample id (searchsorted right)
    int pos = g - soff[s];
    int ns = gstart[g], ne = gstart[g + 1];
    float m = gmax[g], den = gden[g];
    int t = threadIdx.x;
    if (t < FDIM) {
        float acc = 0.0f;
        for (int n = ns; n < ne; ++n) acc += expf(gate[n] - m) * H[(size_t)n * FPAD + t];
        out[((size_t)s * MAXG + pos) * FDIM + t] = acc / den;
    }
}

// ------------------------------------------------------------------ launcher

extern "C" void kernel_launch(void* const* d_in, const int* in_sizes, int n_in,
                              void* d_out, int out_size, void* d_ws, size_t ws_size,
                              hipStream_t stream) {
    const float* x      = (const float*)d_in[0];
    const float* Ws     = (const float*)d_in[1];
    const float* bs     = (const float*)d_in[2];
    const float* w_gate = (const float*)d_in[3];
    const float* b_gate = (const float*)d_in[4];
    const int* src       = (const int*)d_in[5];
    const int* dst       = (const int*)d_in[6];
    const int* graph_ids = (const int*)d_in[7];
    const int* num       = (const int*)d_in[8];
    float* out  = (float*)d_out;

    const int N  = in_sizes[7];
    const int E  = in_sizes[5];
    const int Bn = in_sizes[8];
    const int F  = in_sizes[3];            // 31
    const int L  = in_sizes[2] / F;        // 5
    const int nW = in_sizes[1];            // L * 3F * F
    const int WperL = nW / L;              // 3F*F
    const int MAXG = out_size / (Bn * F);  // 120
    const int Gmax = Bn * MAXG;

    const int nbuk = (N + CW - 1) / CW;    // 196 for N=400K (<= MAXBUK)
    const int cap  = E / nbuk + E / (8 * nbuk) + 2048;  // mean + ~33 sigma slack

    // ---- workspace carve-up (same footprint as the passing R2 layout)
    char* p = (char*)d_ws;
    auto alloc = [&](size_t bytes) {
        void* r = (void*)p;
        p += (bytes + 255) & ~(size_t)255;
        return r;
    };
    float* HA    = (float*)alloc((size_t)N * FPAD * 4);
    float* HB    = (float*)alloc((size_t)N * FPAD * 4);
    float* HC    = (float*)alloc((size_t)N * FPAD * 4);
    int*   colw  = (int*)alloc((size_t)E * 4);
    int*   gcnt  = (int*)alloc((size_t)nbuk * 4);
    int*   deg   = (int*)alloc((size_t)N * 4);
    int*   rowp  = (int*)alloc((size_t)(N + 1) * 4);
    float* normv = (float*)alloc((size_t)N * 4);
    float* gatev = (float*)alloc((size_t)N * 4);
    float* gmax  = (float*)alloc((size_t)Gmax * 4);
    float* gden  = (float*)alloc((size_t)Gmax * 4);
    int*   gstart= (int*)alloc((size_t)(Gmax + 1) * 4);
    int*   soff  = (int*)alloc((size_t)(Bn + 1) * 4);
    const int NB = (N + 255) / 256;
    int*   parts = (int*)alloc((size_t)NB * 4);

    // bkt aliases HB: nbuk*cap*4 (~30 MB) <= N*FPAD*4 (~51 MB). Stream order
    // guarantees bucket_fill reads finish before the first spmm writes HB.
    int* bkt = (int*)HB;

    // ---- zero init
    hipMemsetAsync(gcnt, 0, (size_t)nbuk * 4, stream);
    hipMemsetAsync(gstart, 0, (size_t)(Gmax + 1) * 4, stream);
    hipMemsetAsync(d_out, 0, (size_t)out_size * sizeof(float), stream);

    // ---- CSR build via LDS-staged multisplit (no scattered global atomics)
    const int NT = (E + TILE - 1) / TILE;
    multisplit_kernel<<<NT, 256, 0, stream>>>(src, dst, gcnt, bkt, cap, E, nbuk);
    bucket_deg_kernel<<<nbuk, 1024, 0, stream>>>(bkt, gcnt, deg, cap, N);
    scan_block_kernel<<<NB, 256, 0, stream>>>(deg, rowp, parts, N);
    scan_partials_kernel<<<1, 256, 0, stream>>>(parts, NB);
    finalize_kernel<<<NB, 256, 0, stream>>>(rowp, parts, deg, normv, N, E);
    bucket_fill_kernel<<<nbuk, 1024, 0, stream>>>(bkt, gcnt, rowp, colw, cap, N);

    // ---- input layout (pad 31 -> 32)
    cast_x_kernel<<<(N * FPAD + 255) / 256, 256, 0, stream>>>(x, HA, N);

    // ---- 5 TAGConv layers
    const int SB = (N + 31) / 32;
    for (int l = 0; l < L; ++l) {
        spmm_kernel<<<SB, 256, 0, stream>>>(HA, HB, rowp, colw, normv, N);
        spmm_kernel<<<SB, 256, 0, stream>>>(HB, HC, rowp, colw, normv, N);
        linear_relu_kernel<<<NB, 256, 0, stream>>>(HA, HB, HC, Ws + (size_t)l * WperL,
                                                   bs + (size_t)l * F, HA, N);
    }

    // ---- gated attention pooling + padded scatter
    gate_kernel<<<NB, 256, 0, stream>>>(HA, w_gate, b_gate, gatev, N);
    boundaries_kernel<<<NB, 256, 0, stream>>>(graph_ids, gstart, N);
    soff_scan_kernel<<<1, 64, 0, stream>>>(num, soff, Bn);
    graph_reduce_kernel<<<Gmax, 64, 0, stream>>>(gatev, gstart, soff, Bn, gmax, gden);
    rep_scatter_kernel<<<Gmax, 64, 0, stream>>>(HA, gatev, gstart, soff, Bn, MAXG,
                                                gmax, gden, out);
    (void)n_in; (void)ws_size;
}